// Round 9
// baseline (273.647 us; speedup 1.0000x reference)
//
#include <hip/hip_runtime.h>

// Problem constants
constexpr int B  = 2;
constexpr int N  = 2048;
constexpr int H  = 16;
constexpr int C  = 256;
constexpr int J  = C + 1 + N;    // 2305
constexpr int Jp = 2368;         // J padded to multiple of 64
constexpr int NT = Jp / 64;      // 37 j-tiles
constexpr float EPS = 1e-5f;
constexpr float LOG2E = 1.4426950408889634f;

typedef __bf16 bf16x8 __attribute__((ext_vector_type(8)));
typedef float  f32x4  __attribute__((ext_vector_type(4)));
typedef unsigned int uint4v __attribute__((ext_vector_type(4)));
typedef __attribute__((address_space(3))) unsigned int lds_u32;
typedef const __attribute__((address_space(1))) unsigned int glb_u32;

__device__ inline void load_lds16(const void* g, void* l) {
    __builtin_amdgcn_global_load_lds((glb_u32*)g, (lds_u32*)l, 16, 0, 0);
}
__device__ inline unsigned short f2bf(float f) {
    unsigned int u = __builtin_bit_cast(unsigned int, f);
    u += 0x7fffu + ((u >> 16) & 1u);
    return (unsigned short)(u >> 16);
}
__device__ inline unsigned int packbf2(float a, float b) {
    union { __bf16 h[2]; unsigned int u; } cv;
    cv.h[0] = (__bf16)a;
    cv.h[1] = (__bf16)b;
    return cv.u;
}
__device__ inline float fexp2(float x) {
    float r;
    asm("v_exp_f32 %0, %1" : "=v"(r) : "v"(x));
    return r;
}
__device__ inline f32x4 mfma16(bf16x8 a, bf16x8 b, f32x4 c) {
    return __builtin_amdgcn_mfma_f32_16x16x32_bf16(a, b, c, 0, 0, 0);
}
// 16B load from a 4B-aligned pointer (J odd -> bias rows only dword-aligned).
__device__ inline f32x4 loadu4(const float* p) {
    f32x4 r;
    __builtin_memcpy(&r, p, 16);
    return r;
}

// ---------------------------------------------------------------------------
// Kernel 0: mask sniff + build additive mask maskf[b][Jp] (0 keep / -1e30 drop).
__global__ void mask_prep(const void* __restrict__ mraw, float* __restrict__ maskf) {
    __shared__ int bad_int, bad_f32;
    const int t = threadIdx.x;
    if (t == 0) { bad_int = 0; bad_f32 = 0; }
    __syncthreads();
    const unsigned int* w = (const unsigned int*)mraw;
    int li = 0, lf = 0;
    for (int i = t; i < 1152; i += 256) {
        unsigned int v = w[i];
        if (v > 1u) li = 1;
        if (v != 0u && v != 0x3F800000u) lf = 1;
    }
    if (li) atomicOr(&bad_int, 1);
    if (lf) atomicOr(&bad_f32, 1);
    __syncthreads();
    const int mode = (!bad_int) ? 0 : ((!bad_f32) ? 1 : 2);
    const unsigned char* bytes = (const unsigned char*)mraw;
    for (int i = t; i < 2 * Jp; i += 256) {
        const int b2 = i / Jp, jp = i - b2 * Jp;
        float v;
        if (jp == 0) v = 0.f;
        else if (jp >= J) v = -1e30f;
        else {
            const int idx = b2 * (C + N) + jp - 1;
            const int keep = (mode == 2) ? (bytes[idx] != 0) : (w[idx] != 0u);
            v = keep ? 0.f : -1e30f;
        }
        maskf[i] = v;
    }
}

// ---------------------------------------------------------------------------
// Kernel 1: zero the pad region of Kb (rows J..Jp) and Vt (cols J..Jp).
__global__ void zero_pads(unsigned short* __restrict__ Kb, unsigned short* __restrict__ Vt) {
    const int t = threadIdx.x;
    for (int i = t; i < 2 * 63 * 64; i += 256) {
        const int b2 = i / (63 * 64);
        const int rr = (i / 64) % 63;
        const int d  = i % 64;
        Kb[(size_t)(b2 * Jp + J + rr) * 64 + d] = 0;
    }
    for (int i = t; i < 2 * 64 * 63; i += 256) {
        const int b2 = i / (64 * 63);
        const int d  = (i / 63) % 64;
        const int cc = i % 63;
        Vt[(size_t)(b2 * 64 + d) * Jp + J + cc] = 0;
    }
}

// ---------------------------------------------------------------------------
// Kernel 2: layernorm over 1024 (beta=0). BF16OUT: write bf16, else f32.
template <int BF16OUT>
__global__ void __launch_bounds__(256) ln1024(const float* __restrict__ x,
                                              const float* __restrict__ gamma,
                                              void* __restrict__ outp) {
    const int row = blockIdx.x;
    const int t = threadIdx.x;
    const float* xr = x + (size_t)row * 1024;
    float4 v = ((const float4*)xr)[t];
    float s  = v.x + v.y + v.z + v.w;
    float ss = v.x * v.x + v.y * v.y + v.z * v.z + v.w * v.w;
    #pragma unroll
    for (int o = 1; o < 64; o <<= 1) {
        s  += __shfl_xor(s, o);
        ss += __shfl_xor(ss, o);
    }
    __shared__ float red[8];
    const int w = t >> 6;
    if ((t & 63) == 0) { red[w * 2] = s; red[w * 2 + 1] = ss; }
    __syncthreads();
    s  = red[0] + red[2] + red[4] + red[6];
    ss = red[1] + red[3] + red[5] + red[7];
    const float mean = s * (1.0f / 1024.0f);
    const float var  = ss * (1.0f / 1024.0f) - mean * mean;
    const float rstd = rsqrtf(var + EPS);
    const float4 g = ((const float4*)gamma)[t];
    float o0 = (v.x - mean) * rstd * g.x;
    float o1 = (v.y - mean) * rstd * g.y;
    float o2 = (v.z - mean) * rstd * g.z;
    float o3 = (v.w - mean) * rstd * g.w;
    if (BF16OUT) {
        ushort4 u;
        u.x = f2bf(o0); u.y = f2bf(o1); u.z = f2bf(o2); u.w = f2bf(o3);
        *(ushort4*)((unsigned short*)outp + (size_t)row * 1024 + t * 4) = u;
    } else {
        *(float4*)((float*)outp + (size_t)row * 1024 + t * 4) = make_float4(o0, o1, o2, o3);
    }
}

// ---------------------------------------------------------------------------
// Kernel 3: transpose + bf16-convert a weight W(K x Nn) -> WT(Nn x K), *scale.
__global__ void __launch_bounds__(256) transpose_w(const float* __restrict__ W,
                                                   unsigned short* __restrict__ WT,
                                                   int K, int Nn, float scale) {
    __shared__ float lds[64][68];
    const int k0 = blockIdx.x * 64, n0 = blockIdx.y * 64;
    const int t = threadIdx.x;
    const int kk = t >> 4, nn = (t & 15) * 4;
    #pragma unroll
    for (int r = 0; r < 4; r++) {
        const float4 v = *(const float4*)(W + (size_t)(k0 + kk + r * 16) * Nn + n0 + nn);
        lds[kk + r * 16][nn + 0] = v.x;
        lds[kk + r * 16][nn + 1] = v.y;
        lds[kk + r * 16][nn + 2] = v.z;
        lds[kk + r * 16][nn + 3] = v.w;
    }
    __syncthreads();
    const int nr = t >> 2, kc = (t & 3) * 16;
    #pragma unroll
    for (int u4 = 0; u4 < 4; u4++) {
        ushort4 u;
        u.x = f2bf(lds[kc + u4 * 4 + 0][nr] * scale);
        u.y = f2bf(lds[kc + u4 * 4 + 1][nr] * scale);
        u.z = f2bf(lds[kc + u4 * 4 + 2][nr] * scale);
        u.w = f2bf(lds[kc + u4 * 4 + 3][nr] * scale);
        *(ushort4*)(WT + (size_t)(n0 + nr) * K + k0 + kc + u4 * 4) = u;
    }
}

// ---------------------------------------------------------------------------
// Kernel 4: context path: LN(context,512) @ Wctx + bctx -> Kb[0..255] / Vt cols.
__global__ void __launch_bounds__(128) ctx_proj(const float* __restrict__ ctx,
                                                const float* __restrict__ lw,
                                                const float* __restrict__ lb,
                                                const float* __restrict__ Wc,
                                                const float* __restrict__ bc,
                                                unsigned short* __restrict__ Kb,
                                                unsigned short* __restrict__ Vt) {
    const int row = blockIdx.x;          // 0..511
    const int b2 = row >> 8, ci = row & 255;
    const int t = threadIdx.x;           // 0..127
    __shared__ float cn[512];
    __shared__ float red[4];
    const float* xr = ctx + (size_t)row * 512;
    float4 v = ((const float4*)xr)[t];
    float s  = v.x + v.y + v.z + v.w;
    float ss = v.x * v.x + v.y * v.y + v.z * v.z + v.w * v.w;
    #pragma unroll
    for (int o = 1; o < 64; o <<= 1) {
        s  += __shfl_xor(s, o);
        ss += __shfl_xor(ss, o);
    }
    const int w = t >> 6;
    if ((t & 63) == 0) { red[w * 2] = s; red[w * 2 + 1] = ss; }
    __syncthreads();
    s  = red[0] + red[2];
    ss = red[1] + red[3];
    const float mean = s * (1.0f / 512.0f);
    const float var  = ss * (1.0f / 512.0f) - mean * mean;
    const float rstd = rsqrtf(var + EPS);
    const float4 g  = ((const float4*)lw)[t];
    const float4 be = ((const float4*)lb)[t];
    float4 c4;
    c4.x = (v.x - mean) * rstd * g.x + be.x;
    c4.y = (v.y - mean) * rstd * g.y + be.y;
    c4.z = (v.z - mean) * rstd * g.z + be.z;
    c4.w = (v.w - mean) * rstd * g.w + be.w;
    *(float4*)&cn[t * 4] = c4;
    __syncthreads();
    float acc = bc[t];
    #pragma unroll 8
    for (int d = 0; d < 512; d++) acc = fmaf(cn[d], Wc[d * 128 + t], acc);
    const unsigned short bv = f2bf(acc);
    if (t < 64) Kb[(size_t)(b2 * Jp + ci) * 64 + t] = bv;
    else        Vt[(size_t)(b2 * 64 + (t - 64)) * Jp + ci] = bv;
}

// ---------------------------------------------------------------------------
// Kernel 5: null token -> Kb row 256 / Vt col 256.
__global__ void null_fill(const float* __restrict__ nkv,
                          unsigned short* __restrict__ Kb, unsigned short* __restrict__ Vt) {
    const int b2 = blockIdx.x;
    const int t = threadIdx.x;   // 0..63
    Kb[(size_t)(b2 * Jp + 256) * 64 + t] = f2bf(nkv[t]);
    Vt[(size_t)(b2 * 64 + t) * Jp + 256] = f2bf(nkv[64 + t]);
}

// ---------------------------------------------------------------------------
// Kernel 6: bf16 MFMA GEMM, 128x128 tile, BK=64, 4 waves, 2-phase dbuf.
// A (M,K) bf16 row-major; BT (Nn,K) bf16 row-major (= B^T).
// MODE 0: Cf f32 [M,Nn].  MODE 1: Cb bf16 [M,Nn].  MODE 2: kv scatter.
template <int MODE>
__global__ void __launch_bounds__(256, 2) gemm_bf16(
        const unsigned short* __restrict__ A, const unsigned short* __restrict__ BT,
        float* __restrict__ Cf, unsigned short* __restrict__ Cb,
        unsigned short* __restrict__ Kb, unsigned short* __restrict__ Vt,
        int M, int Nn, int K) {
    __shared__ __align__(16) unsigned char smem[65536];
    const int t = threadIdx.x;
    const int w = t >> 6, lane = t & 63;
    const int g = lane >> 4, ln15 = lane & 15;
    const int wm = w >> 1, wn = w & 1;
    const int row0 = blockIdx.x * 128, col0 = blockIdx.y * 128;
    const int nk = K >> 6;
    const int ls = lane >> 3;
    const int swz = (lane & 7) ^ ls;

    f32x4 acc[4][4];
    #pragma unroll
    for (int i = 0; i < 4; i++)
        #pragma unroll
        for (int jj = 0; jj < 4; jj++)
            acc[i][jj] = (f32x4){0.f, 0.f, 0.f, 0.f};

    auto stage = [&](int kt, int cur) {
        if (w < 2) {
            const unsigned short* src = A + (size_t)(row0 + w * 64 + ls) * K + kt * 64 + swz * 8;
            unsigned char* dst = smem + cur * 16384 + w * 8192;
            #pragma unroll
            for (int i = 0; i < 8; i++)
                load_lds16(src + (size_t)i * 8 * K, dst + i * 1024);
        } else {
            const unsigned short* src = BT + (size_t)(col0 + (w - 2) * 64 + ls) * K + kt * 64 + swz * 8;
            unsigned char* dst = smem + 32768 + cur * 16384 + (w - 2) * 8192;
            #pragma unroll
            for (int i = 0; i < 8; i++)
                load_lds16(src + (size_t)i * 8 * K, dst + i * 1024);
        }
    };

    stage(0, 0);
    __syncthreads();
    for (int kt = 0; kt < nk; kt++) {
        const int cur = kt & 1;
        if (kt + 1 < nk) stage(kt + 1, cur ^ 1);
        const unsigned char* As = smem + cur * 16384;
        const unsigned char* Bs = smem + 32768 + cur * 16384;
        #pragma unroll
        for (int ks = 0; ks < 2; ks++) {
            bf16x8 af[4], bf[4];
            #pragma unroll
            for (int mq = 0; mq < 4; mq++)
                af[mq] = *(const bf16x8*)(As + (wm * 64 + mq * 16 + ln15) * 128 +
                                          ((ks * 64 + g * 16) ^ ((ln15 & 7) << 4)));
            #pragma unroll
            for (int nq = 0; nq < 4; nq++)
                bf[nq] = *(const bf16x8*)(Bs + (wn * 64 + nq * 16 + ln15) * 128 +
                                          ((ks * 64 + g * 16) ^ ((ln15 & 7) << 4)));
            #pragma unroll
            for (int mq = 0; mq < 4; mq++)
                #pragma unroll
                for (int nq = 0; nq < 4; nq++)
                    acc[mq][nq] = mfma16(af[mq], bf[nq], acc[mq][nq]);
        }
        __syncthreads();
    }

    #pragma unroll
    for (int mq = 0; mq < 4; mq++) {
        #pragma unroll
        for (int nq = 0; nq < 4; nq++) {
            #pragma unroll
            for (int r = 0; r < 4; r++) {
                const int gr = row0 + wm * 64 + mq * 16 + g * 4 + r;
                const int gc = col0 + wn * 64 + nq * 16 + ln15;
                if (MODE == 0) {
                    Cf[(size_t)gr * Nn + gc] = acc[mq][nq][r];
                } else if (MODE == 1) {
                    Cb[(size_t)gr * Nn + gc] = f2bf(acc[mq][nq][r]);
                } else {
                    const int b2 = gr >> 11, tok = gr & 2047;
                    const unsigned short v = f2bf(acc[mq][nq][r]);
                    if (gc < 64) Kb[(size_t)(b2 * Jp + 257 + tok) * 64 + gc] = v;
                    else         Vt[(size_t)(b2 * 64 + gc - 64) * Jp + 257 + tok] = v;
                }
            }
        }
    }
}

// ---------------------------------------------------------------------------
// Kernel 7: flash attention v9 — CU-exclusive block, 2x K/V reuse per LDS read.
// Grid (16,16): one 512-thread block (8 waves) per CU; block covers 128 q-rows
// x both batches. Wave (b2 = w&1, wq = w>>1) owns batch b2, 32 q-rows
// (two 16-row Q fragments). Per j-tile the CU stages ONCE (double-buffered):
// K/V 32 KB (global_load_lds, swizzled src) + bias tile 32 KB f32 (coalesced
// loads -> regs -> padded LDS [128][68]). Each K/V LDS fragment read feeds
// TWO Q fragments -> LDS instrs per CU halve vs v8. exp2 domain,
// defer-rescale, cvt_pk pack, setprio.
__global__ void __launch_bounds__(512, 2) attn_v9(
        const unsigned short* __restrict__ qb, const unsigned short* __restrict__ Kb,
        const unsigned short* __restrict__ Vt, const float* __restrict__ bias,
        const float* __restrict__ maskf, unsigned short* __restrict__ aout) {
    __shared__ __align__(16) unsigned char smem[135168];   // 64K kv dbuf + 68K bias dbuf
    const int t = threadIdx.x;
    const int w = t >> 6, lane = t & 63;
    const int g = lane >> 4, ln15 = lane & 15;
    const int i0 = blockIdx.x * 128, h = blockIdx.y;
    const int b2 = w & 1, wq = w >> 1;            // wave: batch b2, q-rows i0+wq*32..+31
    const int ls = lane >> 3;
    const int swz = (lane & 7) ^ ls;

    // ---- K/V staging: 8 waves x 4 KB. Waves 0..3: K (kb = w>>1, half = w&1
    // -> 32 j-rows). Waves 4..7: V (vb = (w-4)>>1, half -> 32 d-rows).
    // Buffer layout: K[b] @ cur*32768 + b*8192, V[b] @ +16384 + b*8192.
    auto stage = [&](int jt, int cur) {
        const int j0 = jt * 64;
        const int half = w & 1;
        if (w < 4) {
            const int kb = w >> 1;
            const unsigned short* src = Kb + (size_t)(kb * Jp + j0 + half * 32 + ls) * 64 + swz * 8;
            unsigned char* dst = smem + cur * 32768 + kb * 8192 + half * 4096;
            #pragma unroll
            for (int i = 0; i < 4; i++)
                load_lds16(src + (size_t)i * 8 * 64, dst + i * 1024);
        } else {
            const int vb = (w - 4) >> 1;
            const unsigned short* src = Vt + (size_t)(vb * 64 + half * 32 + ls) * Jp + j0 + swz * 8;
            unsigned char* dst = smem + cur * 32768 + 16384 + vb * 8192 + half * 4096;
            #pragma unroll
            for (int i = 0; i < 4; i++)
                load_lds16(src + (size_t)i * 8 * Jp, dst + i * 1024);
        }
    };

    // ---- Bias staging: [128 q][64 j] f32 -> LDS [128][68] (padded). Each
    // thread: 4 coalesced 16B loads -> named regs (issued a tile early),
    // 4 ds_writes after compute. Thread t covers row t>>2, j-span (t&3)*16..+15.
    const int bq  = t >> 2;          // 0..127
    const int bs0 = (t & 3) * 16;    // f32 column base within the 64-j tile
    const float* biasQrow = bias + ((size_t)h * N + i0 + bq) * J;
    auto bias_issue = [&](int jt, f32x4& r0, f32x4& r1, f32x4& r2, f32x4& r3) {
        const int j0 = jt * 64;
        if (j0 + 64 <= J) {
            r0 = loadu4(biasQrow + j0 + bs0 + 0);
            r1 = loadu4(biasQrow + j0 + bs0 + 4);
            r2 = loadu4(biasQrow + j0 + bs0 + 8);
            r3 = loadu4(biasQrow + j0 + bs0 + 12);
        } else {
            #pragma unroll
            for (int c = 0; c < 4; c++) {
                const int ja = j0 + bs0 + c;
                r0[c] = (ja      < J) ? biasQrow[ja]      : 0.f;
                r1[c] = (ja + 4  < J) ? biasQrow[ja + 4]  : 0.f;
                r2[c] = (ja + 8  < J) ? biasQrow[ja + 8]  : 0.f;
                r3[c] = (ja + 12 < J) ? biasQrow[ja + 12] : 0.f;
            }
        }
    };
    auto bias_write = [&](int cur, const f32x4& r0, const f32x4& r1,
                          const f32x4& r2, const f32x4& r3) {
        float* basep = (float*)(smem + 65536 + cur * 34816) + bq * 68 + bs0;
        *(f32x4*)(basep + 0)  = r0;
        *(f32x4*)(basep + 4)  = r1;
        *(f32x4*)(basep + 8)  = r2;
        *(f32x4*)(basep + 12) = r3;
    };

    // Q fragments (B-operand of swapped QK^T): qq selects 16-row group.
    bf16x8 qf[2][2];
    #pragma unroll
    for (int qq = 0; qq < 2; qq++)
        #pragma unroll
        for (int ks = 0; ks < 2; ks++)
            qf[qq][ks] = *(const bf16x8*)(qb +
                (size_t)(b2 * N + i0 + wq * 32 + qq * 16 + ln15) * 1024 +
                h * 64 + ks * 32 + g * 8);

    float mrun[2] = {-1e30f, -1e30f};
    float lrun[2] = {0.f, 0.f};
    f32x4 outA[2][4];
    #pragma unroll
    for (int qq = 0; qq < 2; qq++)
        #pragma unroll
        for (int nq = 0; nq < 4; nq++)
            outA[qq][nq] = (f32x4){0.f, 0.f, 0.f, 0.f};

    const int srclA = ln15 + (((2 * g + 0) & 3) << 4);
    const int srclB = ln15 + (((2 * g + 1) & 3) << 4);

    auto compute = [&](int jt, int cur) {
        const int j0 = jt * 64;
        const unsigned char* Kl = smem + cur * 32768 + b2 * 8192;
        const unsigned char* Vl = smem + cur * 32768 + 16384 + b2 * 8192;
        const float* bbase = (const float*)(smem + 65536 + cur * 34816);

        f32x4 mk[4];
        #pragma unroll
        for (int jqm = 0; jqm < 4; jqm++)
            mk[jqm] = *(const f32x4*)(maskf + b2 * Jp + j0 + jqm * 16 + g * 4);

        // QK^T for both q-groups; each ka read feeds 2 MFMAs.
        f32x4 S[2][4];
        #pragma unroll
        for (int qq = 0; qq < 2; qq++)
            #pragma unroll
            for (int jqm = 0; jqm < 4; jqm++)
                S[qq][jqm] = (f32x4){0.f, 0.f, 0.f, 0.f};
        #pragma unroll
        for (int ks = 0; ks < 2; ks++) {
            bf16x8 ka[4];
            #pragma unroll
            for (int jqm = 0; jqm < 4; jqm++)
                ka[jqm] = *(const bf16x8*)(Kl + (jqm * 16 + ln15) * 128 +
                                           ((ks * 64 + g * 16) ^ ((ln15 & 7) << 4)));
            __builtin_amdgcn_s_setprio(1);
            #pragma unroll
            for (int jqm = 0; jqm < 4; jqm++) {
                S[0][jqm] = mfma16(ka[jqm], qf[0][ks], S[0][jqm]);
                S[1][jqm] = mfma16(ka[jqm], qf[1][ks], S[1][jqm]);
            }
            __builtin_amdgcn_s_setprio(0);
        }

        unsigned int Wp[2][4][2];
        #pragma unroll
        for (int qq = 0; qq < 2; qq++) {
            const float* bb = bbase + (wq * 32 + qq * 16 + ln15) * 68;
            float sv[4][4];
            #pragma unroll
            for (int jqm = 0; jqm < 4; jqm++) {
                const f32x4 br = *(const f32x4*)(bb + jqm * 16 + g * 4);
                #pragma unroll
                for (int r = 0; r < 4; r++)
                    sv[jqm][r] = fmaf(br[r], LOG2E, S[qq][jqm][r]) + mk[jqm][r];
            }

            float tmj[4];
            #pragma unroll
            for (int jqm = 0; jqm < 4; jqm++)
                tmj[jqm] = fmaxf(fmaxf(sv[jqm][0], sv[jqm][1]), fmaxf(sv[jqm][2], sv[jqm][3]));
            float tm = fmaxf(fmaxf(tmj[0], tmj[1]), fmaxf(tmj[2], tmj[3]));
            tm = fmaxf(tm, __shfl_xor(tm, 16));
            tm = fmaxf(tm, __shfl_xor(tm, 32));

            if (!__all(tm <= mrun[qq])) {   // exact skip: rescale only if max grew
                const float mnew = fmaxf(mrun[qq], tm);
                const float cor = fexp2(mrun[qq] - mnew);
                mrun[qq] = mnew;
                float corr[4];
                #pragma unroll
                for (int r = 0; r < 4; r++) corr[r] = __shfl(cor, g * 4 + r, 64);
                #pragma unroll
                for (int nq = 0; nq < 4; nq++)
                    #pragma unroll
                    for (int r = 0; r < 4; r++)
                        outA[qq][nq][r] *= corr[r];
                lrun[qq] *= cor;
            }
            const float mcur = mrun[qq];

            float p[4][4];
            #pragma unroll
            for (int jqm = 0; jqm < 4; jqm++)
                #pragma unroll
                for (int r = 0; r < 4; r++)
                    p[jqm][r] = fexp2(sv[jqm][r] - mcur);
            float tsj[4];
            #pragma unroll
            for (int jqm = 0; jqm < 4; jqm++)
                tsj[jqm] = (p[jqm][0] + p[jqm][1]) + (p[jqm][2] + p[jqm][3]);
            float ts = (tsj[0] + tsj[1]) + (tsj[2] + tsj[3]);
            ts += __shfl_xor(ts, 16);
            ts += __shfl_xor(ts, 32);
            lrun[qq] += ts;

            #pragma unroll
            for (int jqm = 0; jqm < 4; jqm++) {
                Wp[qq][jqm][0] = packbf2(p[jqm][0], p[jqm][1]);
                Wp[qq][jqm][1] = packbf2(p[jqm][2], p[jqm][3]);
            }
        }

        // PV: each vf read feeds both q-groups.
        #pragma unroll
        for (int ks = 0; ks < 2; ks++) {
            bf16x8 pa[2];
            #pragma unroll
            for (int qq = 0; qq < 2; qq++) {
                uint4v wd;
                #pragma unroll
                for (int widx = 0; widx < 4; widx++) {
                    const int srcl = (widx >> 1) ? srclB : srclA;
                    const int t0 = __shfl((int)Wp[qq][ks * 2 + 0][widx & 1], srcl, 64);
                    const int t1 = __shfl((int)Wp[qq][ks * 2 + 1][widx & 1], srcl, 64);
                    wd[widx] = (unsigned int)((g >> 1) ? t1 : t0);
                }
                pa[qq] = __builtin_bit_cast(bf16x8, wd);
            }
            bf16x8 vf[4];
            #pragma unroll
            for (int nq = 0; nq < 4; nq++)
                vf[nq] = *(const bf16x8*)(Vl + (nq * 16 + ln15) * 128 +
                                          ((ks * 64 + g * 16) ^ ((ln15 & 7) << 4)));
            __builtin_amdgcn_s_setprio(1);
            #pragma unroll
            for (int nq = 0; nq < 4; nq++) {
                outA[0][nq] = mfma16(pa[0], vf[nq], outA[0][nq]);
                outA[1][nq] = mfma16(pa[1], vf[nq], outA[1][nq]);
            }
            __builtin_amdgcn_s_setprio(0);
        }
    };

    // ---- pipeline: bias regs in flight during compute; all LDS dbuf'd.
    f32x4 bR0, bR1, bR2, bR3;
    bias_issue(0, bR0, bR1, bR2, bR3);
    stage(0, 0);
    bias_write(0, bR0, bR1, bR2, bR3);
    __syncthreads();
    for (int jt = 0; jt < NT; jt++) {
        const int cur = jt & 1;
        if (jt + 1 < NT) {
            bias_issue(jt + 1, bR0, bR1, bR2, bR3);   // HBM latency hides under compute
            stage(jt + 1, cur ^ 1);
        }
        compute(jt, cur);
        if (jt + 1 < NT) bias_write(cur ^ 1, bR0, bR1, bR2, bR3);
        __syncthreads();
    }

    #pragma unroll
    for (int qq = 0; qq < 2; qq++) {
        const float inv = 1.0f / lrun[qq];
        float invr[4];
        #pragma unroll
        for (int r = 0; r < 4; r++) invr[r] = __shfl(inv, g * 4 + r, 64);
        #pragma unroll
        for (int nq = 0; nq < 4; nq++)
            #pragma unroll
            for (int r = 0; r < 4; r++)
                aout[(size_t)(b2 * N + i0 + wq * 32 + qq * 16 + g * 4 + r) * 1024 +
                     h * 64 + nq * 16 + ln15] = f2bf(outA[qq][nq][r] * invr[r]);
    }
}

// ---------------------------------------------------------------------------
extern "C" void kernel_launch(void* const* d_in, const int* in_sizes, int n_in,
                              void* d_out, int out_size, void* d_ws, size_t ws_size,
                              hipStream_t stream) {
    const float* x         = (const float*)d_in[0];
    const float* context   = (const float*)d_in[1];
    const void*  mask      = d_in[2];
    const float* bias      = (const float*)d_in[3];
    const float* norm_g    = (const float*)d_in[4];
    const float* null_kv   = (const float*)d_in[5];
    const float* Wq        = (const float*)d_in[6];
    const float* Wkv       = (const float*)d_in[7];
    const float* ctx_ln_w  = (const float*)d_in[8];
    const float* ctx_ln_b  = (const float*)d_in[9];
    const float* Wctx      = (const float*)d_in[10];
    const float* bctx      = (const float*)d_in[11];
    const float* Wout      = (const float*)d_in[12];
    const float* out_gamma = (const float*)d_in[13];
    float* out = (float*)d_out;

    unsigned char* wsb = (unsigned char*)d_ws;
    unsigned short* xnb   = (unsigned short*)(wsb + 0);          //  8 MB bf16
    unsigned short* qbb   = (unsigned short*)(wsb + 8388608);    //  8 MB bf16
    float*          y     = (float*)(wsb + 0);                   // 16 MB f32 (overlays xnb+qbb, both dead)
    unsigned short* aoutp = (unsigned short*)(wsb + 16777216);   //  8 MB bf16
    unsigned short* KbP   = (unsigned short*)(wsb + 25165824);   // 2*Jp*64 bf16
    unsigned short* VtP   = (unsigned short*)(wsb + 25772032);   // 2*64*Jp bf16
    float*          maskf = (float*)(wsb + 26378240);            // 2*Jp f32
    unsigned short* WqT   = (unsigned short*)(wsb + 26397184);   // 2 MB
    unsigned short* WkvT  = (unsigned short*)(wsb + 28494336);   // 256 KB
    unsigned short* WoutT = (unsigned short*)(wsb + 28756480);   // 2 MB

    mask_prep<<<1, 256, 0, stream>>>(mask, maskf);
    zero_pads<<<1, 256, 0, stream>>>(KbP, VtP);
    ln1024<1><<<B * N, 256, 0, stream>>>(x, norm_g, xnb);
    // fold Dh^-0.5 * log2e into Wq so attention works in exp2 domain
    transpose_w<<<dim3(16, 16), 256, 0, stream>>>(Wq, WqT, 1024, 1024, 0.125f * LOG2E);
    transpose_w<<<dim3(16, 2), 256, 0, stream>>>(Wkv, WkvT, 1024, 128, 1.0f);
    transpose_w<<<dim3(16, 16), 256, 0, stream>>>(Wout, WoutT, 1024, 1024, 1.0f);
    ctx_proj<<<B * C, 128, 0, stream>>>(context, ctx_ln_w, ctx_ln_b, Wctx, bctx, KbP, VtP);
    null_fill<<<B, 64, 0, stream>>>(null_kv, KbP, VtP);
    // q = LN(x) @ (Wq*scale) -> bf16 (4096 x 1024)
    gemm_bf16<1><<<dim3(32, 8), 256, 0, stream>>>(xnb, WqT, nullptr, qbb, nullptr, nullptr, 4096, 1024, 1024);
    // k,v = LN(x) @ Wkv -> scatter bf16 into Kb rows / Vt cols 257..2304
    gemm_bf16<2><<<dim3(32, 1), 256, 0, stream>>>(xnb, WkvT, nullptr, nullptr, KbP, VtP, 4096, 128, 1024);
    attn_v9<<<dim3(16, 16), 512, 0, stream>>>(qbb, KbP, VtP, bias, maskf, aoutp);
    // y = attn_out @ Wout -> f32
    gemm_bf16<0><<<dim3(32, 8), 256, 0, stream>>>(aoutp, WoutT, y, nullptr, nullptr, nullptr, 4096, 1024, 1024);
    ln1024<0><<<B * N, 256, 0, stream>>>(y, out_gamma, out);
}

// Round 11
// 254.010 us; speedup vs baseline: 1.0773x; 1.0773x over previous
//
#include <hip/hip_runtime.h>

// Problem constants
constexpr int B  = 2;
constexpr int N  = 2048;
constexpr int H  = 16;
constexpr int C  = 256;
constexpr int J  = C + 1 + N;    // 2305
constexpr int Jp = 2368;         // J padded to multiple of 64
constexpr int NT = Jp / 64;      // 37 j-tiles
constexpr float EPS = 1e-5f;
constexpr float LOG2E = 1.4426950408889634f;

typedef __bf16 bf16x8 __attribute__((ext_vector_type(8)));
typedef float  f32x4  __attribute__((ext_vector_type(4)));
typedef float  f32x16 __attribute__((ext_vector_type(16)));
typedef unsigned int uint4v __attribute__((ext_vector_type(4)));
typedef __attribute__((address_space(3))) unsigned int lds_u32;
typedef const __attribute__((address_space(1))) unsigned int glb_u32;

__device__ inline void load_lds16(const void* g, void* l) {
    __builtin_amdgcn_global_load_lds((glb_u32*)g, (lds_u32*)l, 16, 0, 0);
}
__device__ inline unsigned short f2bf(float f) {
    unsigned int u = __builtin_bit_cast(unsigned int, f);
    u += 0x7fffu + ((u >> 16) & 1u);
    return (unsigned short)(u >> 16);
}
__device__ inline unsigned int packbf2(float a, float b) {
    union { __bf16 h[2]; unsigned int u; } cv;
    cv.h[0] = (__bf16)a;
    cv.h[1] = (__bf16)b;
    return cv.u;
}
__device__ inline float fexp2(float x) {
    float r;
    asm("v_exp_f32 %0, %1" : "=v"(r) : "v"(x));
    return r;
}
__device__ inline f32x4 mfma16(bf16x8 a, bf16x8 b, f32x4 c) {
    return __builtin_amdgcn_mfma_f32_16x16x32_bf16(a, b, c, 0, 0, 0);
}
__device__ inline f32x16 mfma32(bf16x8 a, bf16x8 b, f32x16 c) {
    return __builtin_amdgcn_mfma_f32_32x32x16_bf16(a, b, c, 0, 0, 0);
}
// 16B load from a 4B-aligned pointer (J odd -> bias rows only dword-aligned).
__device__ inline f32x4 loadu4(const float* p) {
    f32x4 r;
    __builtin_memcpy(&r, p, 16);
    return r;
}

// ---------------------------------------------------------------------------
// Kernel 0: mask sniff + build additive mask maskf[b][Jp] (0 keep / -1e30 drop).
__global__ void mask_prep(const void* __restrict__ mraw, float* __restrict__ maskf) {
    __shared__ int bad_int, bad_f32;
    const int t = threadIdx.x;
    if (t == 0) { bad_int = 0; bad_f32 = 0; }
    __syncthreads();
    const unsigned int* w = (const unsigned int*)mraw;
    int li = 0, lf = 0;
    for (int i = t; i < 1152; i += 256) {
        unsigned int v = w[i];
        if (v > 1u) li = 1;
        if (v != 0u && v != 0x3F800000u) lf = 1;
    }
    if (li) atomicOr(&bad_int, 1);
    if (lf) atomicOr(&bad_f32, 1);
    __syncthreads();
    const int mode = (!bad_int) ? 0 : ((!bad_f32) ? 1 : 2);
    const unsigned char* bytes = (const unsigned char*)mraw;
    for (int i = t; i < 2 * Jp; i += 256) {
        const int b2 = i / Jp, jp = i - b2 * Jp;
        float v;
        if (jp == 0) v = 0.f;
        else if (jp >= J) v = -1e30f;
        else {
            const int idx = b2 * (C + N) + jp - 1;
            const int keep = (mode == 2) ? (bytes[idx] != 0) : (w[idx] != 0u);
            v = keep ? 0.f : -1e30f;
        }
        maskf[i] = v;
    }
}

// ---------------------------------------------------------------------------
// Kernel 1: zero the pad region of Kb (rows J..Jp) and Vt (cols J..Jp).
__global__ void zero_pads(unsigned short* __restrict__ Kb, unsigned short* __restrict__ Vt) {
    const int t = threadIdx.x;
    for (int i = t; i < 2 * 63 * 64; i += 256) {
        const int b2 = i / (63 * 64);
        const int rr = (i / 64) % 63;
        const int d  = i % 64;
        Kb[(size_t)(b2 * Jp + J + rr) * 64 + d] = 0;
    }
    for (int i = t; i < 2 * 64 * 63; i += 256) {
        const int b2 = i / (64 * 63);
        const int d  = (i / 63) % 64;
        const int cc = i % 63;
        Vt[(size_t)(b2 * 64 + d) * Jp + J + cc] = 0;
    }
}

// ---------------------------------------------------------------------------
// Kernel 2: layernorm over 1024 (beta=0). BF16OUT: write bf16, else f32.
template <int BF16OUT>
__global__ void __launch_bounds__(256) ln1024(const float* __restrict__ x,
                                              const float* __restrict__ gamma,
                                              void* __restrict__ outp) {
    const int row = blockIdx.x;
    const int t = threadIdx.x;
    const float* xr = x + (size_t)row * 1024;
    float4 v = ((const float4*)xr)[t];
    float s  = v.x + v.y + v.z + v.w;
    float ss = v.x * v.x + v.y * v.y + v.z * v.z + v.w * v.w;
    #pragma unroll
    for (int o = 1; o < 64; o <<= 1) {
        s  += __shfl_xor(s, o);
        ss += __shfl_xor(ss, o);
    }
    __shared__ float red[8];
    const int w = t >> 6;
    if ((t & 63) == 0) { red[w * 2] = s; red[w * 2 + 1] = ss; }
    __syncthreads();
    s  = red[0] + red[2] + red[4] + red[6];
    ss = red[1] + red[3] + red[5] + red[7];
    const float mean = s * (1.0f / 1024.0f);
    const float var  = ss * (1.0f / 1024.0f) - mean * mean;
    const float rstd = rsqrtf(var + EPS);
    const float4 g = ((const float4*)gamma)[t];
    float o0 = (v.x - mean) * rstd * g.x;
    float o1 = (v.y - mean) * rstd * g.y;
    float o2 = (v.z - mean) * rstd * g.z;
    float o3 = (v.w - mean) * rstd * g.w;
    if (BF16OUT) {
        ushort4 u;
        u.x = f2bf(o0); u.y = f2bf(o1); u.z = f2bf(o2); u.w = f2bf(o3);
        *(ushort4*)((unsigned short*)outp + (size_t)row * 1024 + t * 4) = u;
    } else {
        *(float4*)((float*)outp + (size_t)row * 1024 + t * 4) = make_float4(o0, o1, o2, o3);
    }
}

// ---------------------------------------------------------------------------
// Kernel 3: transpose + bf16-convert a weight W(K x Nn) -> WT(Nn x K), *scale.
__global__ void __launch_bounds__(256) transpose_w(const float* __restrict__ W,
                                                   unsigned short* __restrict__ WT,
                                                   int K, int Nn, float scale) {
    __shared__ float lds[64][68];
    const int k0 = blockIdx.x * 64, n0 = blockIdx.y * 64;
    const int t = threadIdx.x;
    const int kk = t >> 4, nn = (t & 15) * 4;
    #pragma unroll
    for (int r = 0; r < 4; r++) {
        const float4 v = *(const float4*)(W + (size_t)(k0 + kk + r * 16) * Nn + n0 + nn);
        lds[kk + r * 16][nn + 0] = v.x;
        lds[kk + r * 16][nn + 1] = v.y;
        lds[kk + r * 16][nn + 2] = v.z;
        lds[kk + r * 16][nn + 3] = v.w;
    }
    __syncthreads();
    const int nr = t >> 2, kc = (t & 3) * 16;
    #pragma unroll
    for (int u4 = 0; u4 < 4; u4++) {
        ushort4 u;
        u.x = f2bf(lds[kc + u4 * 4 + 0][nr] * scale);
        u.y = f2bf(lds[kc + u4 * 4 + 1][nr] * scale);
        u.z = f2bf(lds[kc + u4 * 4 + 2][nr] * scale);
        u.w = f2bf(lds[kc + u4 * 4 + 3][nr] * scale);
        *(ushort4*)(WT + (size_t)(n0 + nr) * K + k0 + kc + u4 * 4) = u;
    }
}

// ---------------------------------------------------------------------------
// Kernel 4: context path: LN(context,512) @ Wctx + bctx -> Kb[0..255] / Vt cols.
__global__ void __launch_bounds__(128) ctx_proj(const float* __restrict__ ctx,
                                                const float* __restrict__ lw,
                                                const float* __restrict__ lb,
                                                const float* __restrict__ Wc,
                                                const float* __restrict__ bc,
                                                unsigned short* __restrict__ Kb,
                                                unsigned short* __restrict__ Vt) {
    const int row = blockIdx.x;          // 0..511
    const int b2 = row >> 8, ci = row & 255;
    const int t = threadIdx.x;           // 0..127
    __shared__ float cn[512];
    __shared__ float red[4];
    const float* xr = ctx + (size_t)row * 512;
    float4 v = ((const float4*)xr)[t];
    float s  = v.x + v.y + v.z + v.w;
    float ss = v.x * v.x + v.y * v.y + v.z * v.z + v.w * v.w;
    #pragma unroll
    for (int o = 1; o < 64; o <<= 1) {
        s  += __shfl_xor(s, o);
        ss += __shfl_xor(ss, o);
    }
    const int w = t >> 6;
    if ((t & 63) == 0) { red[w * 2] = s; red[w * 2 + 1] = ss; }
    __syncthreads();
    s  = red[0] + red[2];
    ss = red[1] + red[3];
    const float mean = s * (1.0f / 512.0f);
    const float var  = ss * (1.0f / 512.0f) - mean * mean;
    const float rstd = rsqrtf(var + EPS);
    const float4 g  = ((const float4*)lw)[t];
    const float4 be = ((const float4*)lb)[t];
    float4 c4;
    c4.x = (v.x - mean) * rstd * g.x + be.x;
    c4.y = (v.y - mean) * rstd * g.y + be.y;
    c4.z = (v.z - mean) * rstd * g.z + be.z;
    c4.w = (v.w - mean) * rstd * g.w + be.w;
    *(float4*)&cn[t * 4] = c4;
    __syncthreads();
    float acc = bc[t];
    #pragma unroll 8
    for (int d = 0; d < 512; d++) acc = fmaf(cn[d], Wc[d * 128 + t], acc);
    const unsigned short bv = f2bf(acc);
    if (t < 64) Kb[(size_t)(b2 * Jp + ci) * 64 + t] = bv;
    else        Vt[(size_t)(b2 * 64 + (t - 64)) * Jp + ci] = bv;
}

// ---------------------------------------------------------------------------
// Kernel 5: null token -> Kb row 256 / Vt col 256.
__global__ void null_fill(const float* __restrict__ nkv,
                          unsigned short* __restrict__ Kb, unsigned short* __restrict__ Vt) {
    const int b2 = blockIdx.x;
    const int t = threadIdx.x;   // 0..63
    Kb[(size_t)(b2 * Jp + 256) * 64 + t] = f2bf(nkv[t]);
    Vt[(size_t)(b2 * 64 + t) * Jp + 256] = f2bf(nkv[64 + t]);
}

// ---------------------------------------------------------------------------
// Kernel 6: bf16 MFMA GEMM, 128x128 tile, BK=64, 4 waves, 2-phase dbuf.
// A (M,K) bf16 row-major; BT (Nn,K) bf16 row-major (= B^T).
// MODE 0: Cf f32 [M,Nn].  MODE 1: Cb bf16 [M,Nn].  MODE 2: kv scatter.
template <int MODE>
__global__ void __launch_bounds__(256, 2) gemm_bf16(
        const unsigned short* __restrict__ A, const unsigned short* __restrict__ BT,
        float* __restrict__ Cf, unsigned short* __restrict__ Cb,
        unsigned short* __restrict__ Kb, unsigned short* __restrict__ Vt,
        int M, int Nn, int K) {
    __shared__ __align__(16) unsigned char smem[65536];
    const int t = threadIdx.x;
    const int w = t >> 6, lane = t & 63;
    const int g = lane >> 4, ln15 = lane & 15;
    const int wm = w >> 1, wn = w & 1;
    const int row0 = blockIdx.x * 128, col0 = blockIdx.y * 128;
    const int nk = K >> 6;
    const int ls = lane >> 3;
    const int swz = (lane & 7) ^ ls;

    f32x4 acc[4][4];
    #pragma unroll
    for (int i = 0; i < 4; i++)
        #pragma unroll
        for (int jj = 0; jj < 4; jj++)
            acc[i][jj] = (f32x4){0.f, 0.f, 0.f, 0.f};

    auto stage = [&](int kt, int cur) {
        if (w < 2) {
            const unsigned short* src = A + (size_t)(row0 + w * 64 + ls) * K + kt * 64 + swz * 8;
            unsigned char* dst = smem + cur * 16384 + w * 8192;
            #pragma unroll
            for (int i = 0; i < 8; i++)
                load_lds16(src + (size_t)i * 8 * K, dst + i * 1024);
        } else {
            const unsigned short* src = BT + (size_t)(col0 + (w - 2) * 64 + ls) * K + kt * 64 + swz * 8;
            unsigned char* dst = smem + 32768 + cur * 16384 + (w - 2) * 8192;
            #pragma unroll
            for (int i = 0; i < 8; i++)
                load_lds16(src + (size_t)i * 8 * K, dst + i * 1024);
        }
    };

    stage(0, 0);
    __syncthreads();
    for (int kt = 0; kt < nk; kt++) {
        const int cur = kt & 1;
        if (kt + 1 < nk) stage(kt + 1, cur ^ 1);
        const unsigned char* As = smem + cur * 16384;
        const unsigned char* Bs = smem + 32768 + cur * 16384;
        #pragma unroll
        for (int ks = 0; ks < 2; ks++) {
            bf16x8 af[4], bf[4];
            #pragma unroll
            for (int mq = 0; mq < 4; mq++)
                af[mq] = *(const bf16x8*)(As + (wm * 64 + mq * 16 + ln15) * 128 +
                                          ((ks * 64 + g * 16) ^ ((ln15 & 7) << 4)));
            #pragma unroll
            for (int nq = 0; nq < 4; nq++)
                bf[nq] = *(const bf16x8*)(Bs + (wn * 64 + nq * 16 + ln15) * 128 +
                                          ((ks * 64 + g * 16) ^ ((ln15 & 7) << 4)));
            #pragma unroll
            for (int mq = 0; mq < 4; mq++)
                #pragma unroll
                for (int nq = 0; nq < 4; nq++)
                    acc[mq][nq] = mfma16(af[mq], bf[nq], acc[mq][nq]);
        }
        __syncthreads();
    }

    #pragma unroll
    for (int mq = 0; mq < 4; mq++) {
        #pragma unroll
        for (int nq = 0; nq < 4; nq++) {
            #pragma unroll
            for (int r = 0; r < 4; r++) {
                const int gr = row0 + wm * 64 + mq * 16 + g * 4 + r;
                const int gc = col0 + wn * 64 + nq * 16 + ln15;
                if (MODE == 0) {
                    Cf[(size_t)gr * Nn + gc] = acc[mq][nq][r];
                } else if (MODE == 1) {
                    Cb[(size_t)gr * Nn + gc] = f2bf(acc[mq][nq][r]);
                } else {
                    const int b2 = gr >> 11, tok = gr & 2047;
                    const unsigned short v = f2bf(acc[mq][nq][r]);
                    if (gc < 64) Kb[(size_t)(b2 * Jp + 257 + tok) * 64 + gc] = v;
                    else         Vt[(size_t)(b2 * 64 + gc - 64) * Jp + 257 + tok] = v;
                }
            }
        }
    }
}

// ---------------------------------------------------------------------------
// Kernel 7: flash attention v11 — 32x32 MFMA, lane-local softmax, with ALL
// cross-lane movement via verified __shfl_xor(.,32) (no permlane asm).
// Grid (16,16) = 256 blocks = 1/CU, 512 threads (8 waves). Wave (b2 = w&1,
// wq = w>>1) owns batch b2, q-rows i0+wq*32..+31. Swapped QK^T via
// mfma_32x32x16: S^T has q = lane&31 -> max/sum/rescale/inv lane-local;
// only pair-exchange (lane ^ 32) crosses lanes. PV as O^T = mfma32(V^T, P^T).
// Per tile the CU stages ONCE (dbuf): K/V 32 KB + bias 32 KB f32 (stride-76
// rows). LDS 140 KB -> 1 block/CU.
__global__ void __launch_bounds__(512, 2) attn_v11(
        const unsigned short* __restrict__ qb, const unsigned short* __restrict__ Kb,
        const unsigned short* __restrict__ Vt, const float* __restrict__ bias,
        const float* __restrict__ maskf, unsigned short* __restrict__ aout) {
    __shared__ __align__(16) unsigned char smem[143360];   // 64K KV dbuf + 2*38912 bias dbuf
    const int t = threadIdx.x;
    const int w = t >> 6, lane = t & 63;
    const int l31 = lane & 31, hi = lane >> 5;
    const int i0 = blockIdx.x * 128, h = blockIdx.y;
    const int b2 = w & 1, wq = w >> 1;            // wave: batch b2, q-rows i0+wq*32..+31
    const int ls = lane >> 3;
    const int swz = (lane & 7) ^ ls;
    const int rsw = (lane & 7) << 4;              // read swizzle (row&7 == lane&7 for all reads)

    // ---- K/V staging: 8 waves x 4 KB (identical to passing v9).
    auto stage = [&](int jt, int cur) {
        const int j0 = jt * 64;
        const int half = w & 1;
        if (w < 4) {
            const int kb = w >> 1;
            const unsigned short* src = Kb + (size_t)(kb * Jp + j0 + half * 32 + ls) * 64 + swz * 8;
            unsigned char* dst = smem + cur * 32768 + kb * 8192 + half * 4096;
            #pragma unroll
            for (int i = 0; i < 4; i++)
                load_lds16(src + (size_t)i * 8 * 64, dst + i * 1024);
        } else {
            const int vb = (w - 4) >> 1;
            const unsigned short* src = Vt + (size_t)(vb * 64 + half * 32 + ls) * Jp + j0 + swz * 8;
            unsigned char* dst = smem + cur * 32768 + 16384 + vb * 8192 + half * 4096;
            #pragma unroll
            for (int i = 0; i < 4; i++)
                load_lds16(src + (size_t)i * 8 * Jp, dst + i * 1024);
        }
    };

    // ---- Bias staging: [128 q][64 j] f32 -> LDS rows of 76 words.
    const int bq = t >> 2;            // 0..127
    const int bs = (t & 3) * 16;      // word col base
    const float* biasQrow = bias + ((size_t)h * N + i0 + bq) * J;
    auto bias_issue = [&](int jt, f32x4& r0, f32x4& r1, f32x4& r2, f32x4& r3) {
        const int j0 = jt * 64;
        if (j0 + 64 <= J) {
            r0 = loadu4(biasQrow + j0 + bs + 0);
            r1 = loadu4(biasQrow + j0 + bs + 4);
            r2 = loadu4(biasQrow + j0 + bs + 8);
            r3 = loadu4(biasQrow + j0 + bs + 12);
        } else {
            #pragma unroll
            for (int c = 0; c < 4; c++) {
                const int ja = j0 + bs + c;
                r0[c] = (ja      < J) ? biasQrow[ja]      : 0.f;
                r1[c] = (ja + 4  < J) ? biasQrow[ja + 4]  : 0.f;
                r2[c] = (ja + 8  < J) ? biasQrow[ja + 8]  : 0.f;
                r3[c] = (ja + 12 < J) ? biasQrow[ja + 12] : 0.f;
            }
        }
    };
    auto bias_write = [&](int cur, const f32x4& r0, const f32x4& r1,
                          const f32x4& r2, const f32x4& r3) {
        float* basep = (float*)(smem + 65536 + cur * 38912) + bq * 76 + bs;
        *(f32x4*)(basep + 0)  = r0;
        *(f32x4*)(basep + 4)  = r1;
        *(f32x4*)(basep + 8)  = r2;
        *(f32x4*)(basep + 12) = r3;
    };

    // Q fragments (B-operand): q = l31, k-d = ks*16 + hi*8 + e.
    bf16x8 qf[4];
    #pragma unroll
    for (int ks = 0; ks < 4; ks++)
        qf[ks] = *(const bf16x8*)(qb + (size_t)(b2 * N + i0 + wq * 32 + l31) * 1024 +
                                  h * 64 + ks * 16 + hi * 8);

    float mrun = -1e30f, lrun = 0.f;
    f32x16 outA[2];
    outA[0] = (f32x16)0.f;
    outA[1] = (f32x16)0.f;

    auto compute = [&](int jt, int cur) {
        const int j0 = jt * 64;
        const unsigned char* Kl = smem + cur * 32768 + b2 * 8192;
        const unsigned char* Vl = smem + cur * 32768 + 16384 + b2 * 8192;
        const float* bbL = (const float*)(smem + 65536 + cur * 38912) +
                           (wq * 32 + l31) * 76;

        // --- QK^T: S^T[j][q=l31], reg r: j_rel = (r&3) + 8*(r>>2) + 4*hi (+jh*32)
        f32x16 S[2];
        S[0] = (f32x16)0.f;
        S[1] = (f32x16)0.f;
        #pragma unroll
        for (int jh = 0; jh < 2; jh++) {
            const int krow = jh * 32 + l31;
            bf16x8 ka[4];
            #pragma unroll
            for (int ks = 0; ks < 4; ks++)
                ka[ks] = *(const bf16x8*)(Kl + krow * 128 + ((ks * 32 + hi * 16) ^ rsw));
            __builtin_amdgcn_s_setprio(1);
            #pragma unroll
            for (int ks = 0; ks < 4; ks++)
                S[jh] = mfma32(ka[ks], qf[ks], S[jh]);
            __builtin_amdgcn_s_setprio(0);
        }

        // --- bias + mask (log2 domain; Q pre-scaled by 0.125*log2e via Wq)
        float sv[2][16];
        #pragma unroll
        for (int jh = 0; jh < 2; jh++)
            #pragma unroll
            for (int rg = 0; rg < 4; rg++) {
                const f32x4 br = *(const f32x4*)(bbL + jh * 32 + rg * 8 + hi * 4);
                const f32x4 mk = *(const f32x4*)(maskf + b2 * Jp + j0 + jh * 32 + rg * 8 + hi * 4);
                #pragma unroll
                for (int c = 0; c < 4; c++)
                    sv[jh][rg * 4 + c] = fmaf(br[c], LOG2E, S[jh][rg * 4 + c]) + mk[c];
            }

        // --- lane-local max over own 32 j, pair-exchange via shfl_xor(32)
        float tm = sv[0][0];
        #pragma unroll
        for (int jh = 0; jh < 2; jh++)
            #pragma unroll
            for (int r = 0; r < 16; r++)
                tm = fmaxf(tm, sv[jh][r]);
        tm = fmaxf(tm, __shfl_xor(tm, 32));

        if (!__all(tm <= mrun)) {      // exact skip: rescale only if max grew
            const float mnew = fmaxf(mrun, tm);
            const float cor = fexp2(mrun - mnew);
            mrun = mnew;
            #pragma unroll
            for (int i = 0; i < 16; i++) { outA[0][i] *= cor; outA[1][i] *= cor; }
            lrun *= cor;
        }
        const float mcur = mrun;

        // --- exp + lane-local sum + pair-exchange
        float p[2][16];
        float ts = 0.f;
        #pragma unroll
        for (int jh = 0; jh < 2; jh++)
            #pragma unroll
            for (int r = 0; r < 16; r++) {
                p[jh][r] = fexp2(sv[jh][r] - mcur);
                ts += p[jh][r];
            }
        ts += __shfl_xor(ts, 32);
        lrun += ts;

        // --- pack P -> B-operand frags: lane (q,hi) needs
        // P[q][jh*32 + m*16 + hi*8 + e]. Own regs hold j = c+8rg+4hi; partner
        // (lane^32) holds the 4hi-complement. Route via shfl_xor(32)+select.
        #pragma unroll
        for (int jh = 0; jh < 2; jh++) {
            #pragma unroll
            for (int m = 0; m < 2; m++) {
                const unsigned int a0 = packbf2(p[jh][m * 8 + 0], p[jh][m * 8 + 1]);
                const unsigned int a1 = packbf2(p[jh][m * 8 + 2], p[jh][m * 8 + 3]);
                const unsigned int b0 = packbf2(p[jh][m * 8 + 4], p[jh][m * 8 + 5]);
                const unsigned int b1 = packbf2(p[jh][m * 8 + 6], p[jh][m * 8 + 7]);
                const unsigned int xa0 = (unsigned int)__shfl_xor((int)a0, 32);
                const unsigned int xa1 = (unsigned int)__shfl_xor((int)a1, 32);
                const unsigned int xb0 = (unsigned int)__shfl_xor((int)b0, 32);
                const unsigned int xb1 = (unsigned int)__shfl_xor((int)b1, 32);
                uint4v wd;
                wd[0] = hi ? xb0 : a0;    // j = 16m+{0,1} (hi0) / 16m+{8,9} (hi1)
                wd[1] = hi ? xb1 : a1;    // {2,3} / {10,11}
                wd[2] = hi ? b0 : xa0;    // {4,5} / {12,13}
                wd[3] = hi ? b1 : xa1;    // {6,7} / {14,15}
                const bf16x8 pfrag = __builtin_bit_cast(bf16x8, wd);
                bf16x8 va[2];
                #pragma unroll
                for (int dblk = 0; dblk < 2; dblk++)
                    va[dblk] = *(const bf16x8*)(Vl + (dblk * 32 + l31) * 128 +
                               ((jh * 64 + m * 32 + hi * 16) ^ rsw));
                __builtin_amdgcn_s_setprio(1);
                #pragma unroll
                for (int dblk = 0; dblk < 2; dblk++)
                    outA[dblk] = mfma32(va[dblk], pfrag, outA[dblk]);
                __builtin_amdgcn_s_setprio(0);
            }
        }
    };

    // ---- pipeline: bias regs in flight during compute; all LDS dbuf'd.
    f32x4 bR0, bR1, bR2, bR3;
    bias_issue(0, bR0, bR1, bR2, bR3);
    stage(0, 0);
    bias_write(0, bR0, bR1, bR2, bR3);
    __syncthreads();
    for (int jt = 0; jt < NT; jt++) {
        const int cur = jt & 1;
        if (jt + 1 < NT) {
            bias_issue(jt + 1, bR0, bR1, bR2, bR3);   // HBM latency hides under compute
            stage(jt + 1, cur ^ 1);
        }
        compute(jt, cur);
        if (jt + 1 < NT) bias_write(cur ^ 1, bR0, bR1, bR2, bR3);
        __syncthreads();
    }

    // ---- epilogue: inv lane-local (q = l31); write O[q][d] pairs.
    const float inv = 1.0f / lrun;
    unsigned short* orow = aout + (size_t)(b2 * N + i0 + wq * 32 + l31) * 1024 + h * 64;
    #pragma unroll
    for (int dblk = 0; dblk < 2; dblk++)
        #pragma unroll
        for (int rg = 0; rg < 4; rg++)
            #pragma unroll
            for (int c2 = 0; c2 < 2; c2++) {
                const int r = rg * 4 + c2 * 2;
                const unsigned int u = packbf2(outA[dblk][r] * inv, outA[dblk][r + 1] * inv);
                *(unsigned int*)(orow + dblk * 32 + rg * 8 + hi * 4 + c2 * 2) = u;
            }
}

// ---------------------------------------------------------------------------
extern "C" void kernel_launch(void* const* d_in, const int* in_sizes, int n_in,
                              void* d_out, int out_size, void* d_ws, size_t ws_size,
                              hipStream_t stream) {
    const float* x         = (const float*)d_in[0];
    const float* context   = (const float*)d_in[1];
    const void*  mask      = d_in[2];
    const float* bias      = (const float*)d_in[3];
    const float* norm_g    = (const float*)d_in[4];
    const float* null_kv   = (const float*)d_in[5];
    const float* Wq        = (const float*)d_in[6];
    const float* Wkv       = (const float*)d_in[7];
    const float* ctx_ln_w  = (const float*)d_in[8];
    const float* ctx_ln_b  = (const float*)d_in[9];
    const float* Wctx      = (const float*)d_in[10];
    const float* bctx      = (const float*)d_in[11];
    const float* Wout      = (const float*)d_in[12];
    const float* out_gamma = (const float*)d_in[13];
    float* out = (float*)d_out;

    unsigned char* wsb = (unsigned char*)d_ws;
    unsigned short* xnb   = (unsigned short*)(wsb + 0);          //  8 MB bf16
    unsigned short* qbb   = (unsigned short*)(wsb + 8388608);    //  8 MB bf16
    float*          y     = (float*)(wsb + 0);                   // 16 MB f32 (overlays xnb+qbb, both dead)
    unsigned short* aoutp = (unsigned short*)(wsb + 16777216);   //  8 MB bf16
    unsigned short* KbP   = (unsigned short*)(wsb + 25165824);   // 2*Jp*64 bf16
    unsigned short* VtP   = (unsigned short*)(wsb + 25772032);   // 2*64*Jp bf16
    float*          maskf = (float*)(wsb + 26378240);            // 2*Jp f32
    unsigned short* WqT   = (unsigned short*)(wsb + 26397184);   // 2 MB
    unsigned short* WkvT  = (unsigned short*)(wsb + 28494336);   // 256 KB
    unsigned short* WoutT = (unsigned short*)(wsb + 28756480);   // 2 MB

    mask_prep<<<1, 256, 0, stream>>>(mask, maskf);
    zero_pads<<<1, 256, 0, stream>>>(KbP, VtP);
    ln1024<1><<<B * N, 256, 0, stream>>>(x, norm_g, xnb);
    // fold Dh^-0.5 * log2e into Wq so attention works in exp2 domain
    transpose_w<<<dim3(16, 16), 256, 0, stream>>>(Wq, WqT, 1024, 1024, 0.125f * LOG2E);
    transpose_w<<<dim3(16, 2), 256, 0, stream>>>(Wkv, WkvT, 1024, 128, 1.0f);
    transpose_w<<<dim3(16, 16), 256, 0, stream>>>(Wout, WoutT, 1024, 1024, 1.0f);
    ctx_proj<<<B * C, 128, 0, stream>>>(context, ctx_ln_w, ctx_ln_b, Wctx, bctx, KbP, VtP);
    null_fill<<<B, 64, 0, stream>>>(null_kv, KbP, VtP);
    // q = LN(x) @ (Wq*scale) -> bf16 (4096 x 1024)
    gemm_bf16<1><<<dim3(32, 8), 256, 0, stream>>>(xnb, WqT, nullptr, qbb, nullptr, nullptr, 4096, 1024, 1024);
    // k,v = LN(x) @ Wkv -> scatter bf16 into Kb rows / Vt cols 257..2304
    gemm_bf16<2><<<dim3(32, 1), 256, 0, stream>>>(xnb, WkvT, nullptr, nullptr, KbP, VtP, 4096, 128, 1024);
    attn_v11<<<dim3(16, 16), 512, 0, stream>>>(qbb, KbP, VtP, bias, maskf, aoutp);
    // y = attn_out @ Wout -> f32
    gemm_bf16<0><<<dim3(32, 8), 256, 0, stream>>>(aoutp, WoutT, y, nullptr, nullptr, nullptr, 4096, 1024, 1024);
    ln1024<0><<<B * N, 256, 0, stream>>>(y, out_gamma, out);
}